// Round 22
// baseline (173.610 us; speedup 1.0000x reference)
//
#include <hip/hip_runtime.h>
#include <hip/hip_bf16.h>

#define DD 128
#define BSH 8          // 256 nodes per bucket (CSR build)
#define CHUNK 4096     // edges per partition block

typedef __attribute__((ext_vector_type(8))) short short8v;
typedef __attribute__((ext_vector_type(4))) float f32x4;

static __device__ __forceinline__ ushort f2bf(float f) {
    __hip_bfloat16 b = __float2bfloat16(f);
    return *reinterpret_cast<ushort*>(&b);
}

// ------- merged prep: hist + cast + prepw1 + prepw2 + zero(dbin,relcur) -----

__global__ __launch_bounds__(256) void k_prep(const int* __restrict__ ei,
                                              int* __restrict__ hist, int E, int NB, int nblk,
                                              const float* __restrict__ x,
                                              ushort* __restrict__ xbf, int n4, int castBlocks,
                                              const float* __restrict__ Wl1,
                                              const float* __restrict__ Wr1,
                                              ushort* __restrict__ Wt1,
                                              const float* __restrict__ Wl2,
                                              const float* __restrict__ Wr2,
                                              ushort* __restrict__ Wt2,
                                              int* __restrict__ dzero) {
    __shared__ int lh[256];
    int t = threadIdx.x;
    int b = blockIdx.x;

    if (b < nblk) {
        lh[t] = 0;
        __syncthreads();
        int e0 = b * CHUNK;
        int e1 = min(e0 + CHUNK, E);
        for (int e = e0 + t; e < e1; e += 256)
            atomicAdd(&lh[ei[E + e] >> BSH], 1);
        __syncthreads();
        if (t < NB) hist[b * NB + t] = lh[t];
        return;
    }
    b -= nblk;
    if (b < castBlocks) {
        int i = b * 256 + t;
        if (i < n4) {
            float4 v = reinterpret_cast<const float4*>(x)[i];
            ushort4 o;
            o.x = f2bf(v.x); o.y = f2bf(v.y); o.z = f2bf(v.z); o.w = f2bf(v.w);
            reinterpret_cast<ushort4*>(xbf)[i] = o;
        }
        return;
    }
    b -= castBlocks;
    if (b < 256) {
        const float* Wl = (b < 128) ? Wl1 : Wl2;
        const float* Wr = (b < 128) ? Wr1 : Wr2;
        ushort* Wt = (b < 128) ? Wt1 : Wt2;
        int idx = (b & 127) * 256 + t;   // 128*256 = 32768
        int nn = idx >> 8, k = idx & 255;
        float v = (k < 128) ? Wl[k * 128 + nn] : Wr[(k - 128) * 128 + nn];
        Wt[nn * 256 + k] = f2bf(v);
        return;
    }
    // zero role: dbin[64] + relcur[64]
    if (t < 128) dzero[t] = 0;
}

// scatter with SELF-DERIVED offsets (k_hscan folded in): thread t streams
// column t of hist (row-reads are wave-coalesced), computing bucket total and
// prefix up to this block's chunk; LDS scan of totals -> bbase; block 0
// publishes bbase for k_csr. Fill order per bucket identical to before.
__global__ __launch_bounds__(256) void k_scatter(const int* __restrict__ ei,
                                                 const int* __restrict__ hist,
                                                 int* __restrict__ bbase,
                                                 uint* __restrict__ pairs,
                                                 int E, int NB, int nblk) {
    __shared__ int lofs[256];
    __shared__ int lh[256];
    __shared__ int s[256];
    int t = threadIdx.x;
    int blk = blockIdx.x;

    int tot = 0, rel = 0;
    if (t < NB) {
        for (int b2 = 0; b2 < nblk; ++b2) {
            int h = hist[b2 * NB + t];
            if (b2 < blk) rel += h;
            tot += h;
        }
    }
    s[t] = (t < NB) ? tot : 0;
    __syncthreads();
#pragma unroll
    for (int off = 1; off < 256; off <<= 1) {
        int u = (t >= off) ? s[t - off] : 0;
        __syncthreads();
        s[t] += u;
        __syncthreads();
    }
    int base = (t == 0) ? 0 : s[t - 1];
    lofs[t] = base + rel;
    lh[t] = 0;
    if (blk == 0) {
        if (t < NB) bbase[t] = base;
        if (t == 0) bbase[NB] = E;
    }
    __syncthreads();

    int e0 = blk * CHUNK, e1 = min(e0 + CHUNK, E);
    for (int e = e0 + t; e < e1; e += 256) {
        int sN = ei[e];
        int d = ei[E + e];
        int b = d >> BSH;
        int lp = atomicAdd(&lh[b], 1);
        pairs[lofs[b] + lp] = ((uint)(d & 255) << 16) | (uint)sN;
    }
}

// count + scan + rowptr + fill + degree-histogram in ONE kernel
__global__ __launch_bounds__(256) void k_csr(const uint* __restrict__ pairs,
                                             const int* __restrict__ bbase,
                                             int* __restrict__ rowptr,
                                             ushort* __restrict__ eidx,
                                             int* __restrict__ dbin,
                                             int n, int E, int NB) {
    __shared__ int lc[256];
    __shared__ int cur[256];
    __shared__ int dh[64];
    int t = threadIdx.x;
    int b = blockIdx.x;
    int node0 = b << BSH;
    lc[t] = 0;
    if (t < 64) dh[t] = 0;
    __syncthreads();
    int r0 = bbase[b], r1 = bbase[b + 1];
    for (int i = r0 + t; i < r1; i += 256)
        atomicAdd(&lc[pairs[i] >> 16], 1);
    __syncthreads();
    int c0 = lc[t];
#pragma unroll
    for (int off = 1; off < 256; off <<= 1) {
        int u = (t >= off) ? lc[t - off] : 0;
        __syncthreads();
        lc[t] += u;
        __syncthreads();
    }
    int rp = r0 + lc[t] - c0;
    int node = node0 + t;
    if (node < n) {
        rowptr[node] = rp;
        atomicAdd(&dh[min(c0, 63)], 1);
    }
    if (b == NB - 1 && t == 0) rowptr[n] = E;
    cur[t] = rp;
    __syncthreads();
    if (t < 64) atomicAdd(&dbin[t], dh[t]);
    for (int i = r0 + t; i < r1; i += 256) {
        uint pr = pairs[i];
        int p = atomicAdd(&cur[pr >> 16], 1);
        eidx[p] = (ushort)(pr & 0xFFFFu);
    }
}

// degree-sorted permutation fill: each block re-derives the 64-bin exclusive
// prefix from the completed dbin locally, claims slots via relcur atomics.
__global__ __launch_bounds__(256) void k_dfill(const int* __restrict__ rowptr,
                                               const int* __restrict__ dbin,
                                               int* __restrict__ relcur,
                                               int* __restrict__ perm, int n) {
    __shared__ int lh[64], lbase[64], pre[64];
    int t = threadIdx.x;
    if (t < 64) lh[t] = 0;
    __syncthreads();
    int i = blockIdx.x * 256 + t;
    int d = -1;
    if (i < n) {
        d = rowptr[i + 1] - rowptr[i];
        if (d > 63) d = 63;
        atomicAdd(&lh[d], 1);
    }
    __syncthreads();
    if (t < 64) pre[t] = dbin[t];
    __syncthreads();
    for (int off = 1; off < 64; off <<= 1) {
        int v = (t < 64 && t >= off) ? pre[t - off] : 0;
        __syncthreads();
        if (t < 64) pre[t] += v;
        __syncthreads();
    }
    if (t < 64) {
        int base = (t == 0) ? 0 : pre[t - 1];
        lbase[t] = base + atomicAdd(&relcur[t], lh[t]);
        lh[t] = 0;
    }
    __syncthreads();
    if (i < n) {
        int lp = atomicAdd(&lh[d], 1);
        perm[lbase[d] + lp] = i;
    }
}

// ---------------- fused SAGE layer (degree-balanced via perm) ----------------
// Block = 32 slots (similar-degree nodes), 512 thr, __launch_bounds__(512,6):
// VGPR~40, no spill (NOTE: (512,8) forces VGPR 32 -> gather spills, dur 50->81).

#define ACC8(v)                                    \
    acc[0] += __uint_as_float((v).x << 16);        \
    acc[1] += __uint_as_float((v).x & 0xffff0000u);\
    acc[2] += __uint_as_float((v).y << 16);        \
    acc[3] += __uint_as_float((v).y & 0xffff0000u);\
    acc[4] += __uint_as_float((v).z << 16);        \
    acc[5] += __uint_as_float((v).z & 0xffff0000u);\
    acc[6] += __uint_as_float((v).w << 16);        \
    acc[7] += __uint_as_float((v).w & 0xffff0000u);

__global__ __launch_bounds__(512, 6) void k_fused(const ushort* __restrict__ hin,
                                                  const int* __restrict__ rowptr,
                                                  const ushort* __restrict__ eidx,
                                                  const int* __restrict__ perm,
                                                  const ushort* __restrict__ Wt,
                                                  const float* __restrict__ bias,
                                                  void* __restrict__ outp,
                                                  int n, int relu, int outBf16) {
    __shared__ ushort sagg[32][128];    // 8 KB
    __shared__ ushort sroot[32][128];   // 8 KB
    __shared__ int sperm[32];

    int t = threadIdx.x;
    int node0 = blockIdx.x * 32;

    if (t < 32) {
        int slot = node0 + t;
        sperm[t] = (slot < n) ? perm[slot] : (n - 1);
    }
    __syncthreads();

    // ---- Phase A: stage root half (32 rows x 16 chunks, 1 chunk/thread) ----
    {
        int r = t >> 4, c = t & 15;
        int row = sperm[r];
        uint4 v = *reinterpret_cast<const uint4*>(hin + (size_t)row * DD + c * 8);
        int cs = c ^ (r & 15);
        *reinterpret_cast<uint4*>(&sroot[r][cs * 8]) = v;
    }

    // ---- Phase B: gather-aggregate, 4 slots per wave ----
    int wave = t >> 6;
    int lane = t & 63;
    int grp = lane >> 4;
    int c16 = lane & 15;
    {
        int node = sperm[wave * 4 + grp];
        int beg = rowptr[node], end = rowptr[node + 1];
        const uint4* base = reinterpret_cast<const uint4*>(hin);

        float acc[8];
#pragma unroll
        for (int i = 0; i < 8; ++i) acc[i] = 0.f;

        int e = beg;
        for (; e + 8 <= end; e += 8) {
            int id[8];
            uint4 v[8];
#pragma unroll
            for (int j = 0; j < 8; ++j) id[j] = eidx[e + j];
#pragma unroll
            for (int j = 0; j < 8; ++j) v[j] = base[(size_t)id[j] * 16 + c16];
#pragma unroll
            for (int j = 0; j < 8; ++j) { ACC8(v[j]); }
        }
        for (; e < end; e += 4) {
            int m = end - e;
            int i0 = eidx[e];
            int i1 = eidx[e + (m > 1 ? 1 : 0)];
            int i2 = eidx[e + (m > 2 ? 2 : 0)];
            int i3 = eidx[e + (m > 3 ? 3 : 0)];
            uint4 v0 = base[(size_t)i0 * 16 + c16];
            uint4 v1 = base[(size_t)i1 * 16 + c16];
            uint4 v2 = base[(size_t)i2 * 16 + c16];
            uint4 v3 = base[(size_t)i3 * 16 + c16];
            ACC8(v0);
            if (m > 1) { ACC8(v1); }
            if (m > 2) { ACC8(v2); }
            if (m > 3) { ACC8(v3); }
        }

        float inv = 1.0f / fmaxf((float)(end - beg), 1.0f);
        uint4 o;
        o.x = ((uint)f2bf(acc[1] * inv) << 16) | (uint)f2bf(acc[0] * inv);
        o.y = ((uint)f2bf(acc[3] * inv) << 16) | (uint)f2bf(acc[2] * inv);
        o.z = ((uint)f2bf(acc[5] * inv) << 16) | (uint)f2bf(acc[4] * inv);
        o.w = ((uint)f2bf(acc[7] * inv) << 16) | (uint)f2bf(acc[6] * inv);
        int r = wave * 4 + grp;
        int cs = c16 ^ (r & 15);
        *reinterpret_cast<uint4*>(&sagg[r][cs * 8]) = o;
    }
    __syncthreads();

    // ---- Phase C: MFMA GEMM for this block's 32 rows ----
    int lr = lane & 15;
    int lk = lane >> 4;
    int nt = wave;            // 16-col slice

    short8v bf[8];
    const ushort* wbase = Wt + (size_t)(nt * 16 + lr) * 256 + lk * 8;
#pragma unroll
    for (int ks = 0; ks < 8; ++ks)
        bf[ks] = *reinterpret_cast<const short8v*>(wbase + ks * 32);

    int col = nt * 16 + lr;
    float bv = bias[col];

#pragma unroll
    for (int sub = 0; sub < 2; ++sub) {
        int m0 = sub * 16;
        int r = m0 + lr;
        f32x4 acc = (f32x4){0.f, 0.f, 0.f, 0.f};
#pragma unroll
        for (int ks = 0; ks < 4; ++ks) {          // agg half (K = 0..127)
            int cc = ks * 4 + lk;
            int cs = cc ^ (r & 15);
            short8v af = *reinterpret_cast<const short8v*>(&sagg[r][cs * 8]);
            acc = __builtin_amdgcn_mfma_f32_16x16x32_bf16(af, bf[ks], acc, 0, 0, 0);
        }
#pragma unroll
        for (int ks = 0; ks < 4; ++ks) {          // root half (K = 128..255)
            int cc = ks * 4 + lk;
            int cs = cc ^ (r & 15);
            short8v af = *reinterpret_cast<const short8v*>(&sroot[r][cs * 8]);
            acc = __builtin_amdgcn_mfma_f32_16x16x32_bf16(af, bf[ks + 4], acc, 0, 0, 0);
        }

        int slotb = m0 + lk * 4;
#pragma unroll
        for (int q = 0; q < 4; ++q) {
            int row = sperm[slotb + q];
            float v = acc[q] + bv;
            if (relu) v = fmaxf(v, 0.f);
            if (outBf16) {
                reinterpret_cast<ushort*>(outp)[(size_t)row * DD + col] = f2bf(v);
            } else {
                reinterpret_cast<float*>(outp)[(size_t)row * DD + col] = v;
            }
        }
    }
}

// ---------------- launch ----------------

extern "C" void kernel_launch(void* const* d_in, const int* in_sizes, int n_in,
                              void* d_out, int out_size, void* d_ws, size_t ws_size,
                              hipStream_t stream) {
    const float* x   = (const float*)d_in[0];
    const int*   ei  = (const int*)d_in[1];
    const float* Wl1 = (const float*)d_in[2];
    const float* Wr1 = (const float*)d_in[3];
    const float* b1  = (const float*)d_in[4];
    const float* Wl2 = (const float*)d_in[5];
    const float* Wr2 = (const float*)d_in[6];
    const float* b2  = (const float*)d_in[7];
    float* out = (float*)d_out;

    int n = in_sizes[0] / DD;
    int E = in_sizes[1] / 2;

    int NB   = (n + 255) >> 8;          // buckets (<=256 for n<=65536)
    int nblk = (E + CHUNK - 1) / CHUNK; // partition chunks

    char* ws = (char*)d_ws;
    size_t off = 0;
    auto take = [&](size_t bytes) -> void* {
        void* p = ws + off;
        off = (off + bytes + 255) & ~(size_t)255;
        return p;
    };
    int* rowptr    = (int*)take(((size_t)n + 1) * 4);
    int* hist      = (int*)take((size_t)nblk * NB * 4);
    int* bbase     = (int*)take(((size_t)NB + 1) * 4);
    int* dzero     = (int*)take(128 * 4);      // dbin[64] + relcur[64]
    int* dbin      = dzero;
    int* relcur    = dzero + 64;
    int* perm      = (int*)take((size_t)n * 4);
    ushort* eidx   = (ushort*)take((size_t)E * 2 + 16);
    uint* pairs    = (uint*)take((size_t)E * 4);
    ushort* xbf    = (ushort*)take((size_t)n * DD * 2);
    ushort* hbf    = (ushort*)take((size_t)n * DD * 2);
    ushort* Wt1    = (ushort*)take((size_t)DD * 256 * 2);
    ushort* Wt2    = (ushort*)take((size_t)DD * 256 * 2);

    int n4 = n * DD / 4;
    int castBlocks = (n4 + 255) / 256;
    int prepBlocks = nblk + castBlocks + 256 + 1;   // +1 zero role
    int nodeBlocks = (n + 255) / 256;

    k_prep<<<prepBlocks, 256, 0, stream>>>(ei, hist, E, NB, nblk,
                                           x, xbf, n4, castBlocks,
                                           Wl1, Wr1, Wt1, Wl2, Wr2, Wt2, dzero);
    k_scatter<<<nblk, 256, 0, stream>>>(ei, hist, bbase, pairs, E, NB, nblk);
    k_csr<<<NB, 256, 0, stream>>>(pairs, bbase, rowptr, eidx, dbin, n, E, NB);
    k_dfill<<<nodeBlocks, 256, 0, stream>>>(rowptr, dbin, relcur, perm, n);

    int fusedBlocks = (n + 31) / 32;

    // Layer 1: hbf = relu(mean_agg(xbf) @ Wl1 + b1 + xbf @ Wr1)   [bf16 out]
    k_fused<<<fusedBlocks, 512, 0, stream>>>(xbf, rowptr, eidx, perm, Wt1, b1, hbf, n, 1, 1);
    // Layer 2: out = mean_agg(hbf) @ Wl2 + b2 + hbf @ Wr2          [fp32 out]
    k_fused<<<fusedBlocks, 512, 0, stream>>>(hbf, rowptr, eidx, perm, Wt2, b2, out, n, 0, 0);
}

// Round 23
// 149.409 us; speedup vs baseline: 1.1620x; 1.1620x over previous
//
#include <hip/hip_runtime.h>
#include <hip/hip_bf16.h>

#define DD 128
#define BSH 8          // 256 nodes per bucket (CSR build)
#define CHUNK 4096     // edges per partition block

typedef __attribute__((ext_vector_type(8))) short short8v;
typedef __attribute__((ext_vector_type(4))) float f32x4;

static __device__ __forceinline__ ushort f2bf(float f) {
    __hip_bfloat16 b = __float2bfloat16(f);
    return *reinterpret_cast<ushort*>(&b);
}

// ------- merged prep: hist + cast + prepw1 + prepw2 + zero(dbin,relcur) -----

__global__ __launch_bounds__(256) void k_prep(const int* __restrict__ ei,
                                              int* __restrict__ hist, int E, int NB, int nblk,
                                              const float* __restrict__ x,
                                              ushort* __restrict__ xbf, int n4, int castBlocks,
                                              const float* __restrict__ Wl1,
                                              const float* __restrict__ Wr1,
                                              ushort* __restrict__ Wt1,
                                              const float* __restrict__ Wl2,
                                              const float* __restrict__ Wr2,
                                              ushort* __restrict__ Wt2,
                                              int* __restrict__ dzero) {
    __shared__ int lh[256];
    int t = threadIdx.x;
    int b = blockIdx.x;

    if (b < nblk) {
        lh[t] = 0;
        __syncthreads();
        int e0 = b * CHUNK;
        int e1 = min(e0 + CHUNK, E);
        for (int e = e0 + t; e < e1; e += 256)
            atomicAdd(&lh[ei[E + e] >> BSH], 1);
        __syncthreads();
        if (t < NB) hist[b * NB + t] = lh[t];
        return;
    }
    b -= nblk;
    if (b < castBlocks) {
        int i = b * 256 + t;
        if (i < n4) {
            float4 v = reinterpret_cast<const float4*>(x)[i];
            ushort4 o;
            o.x = f2bf(v.x); o.y = f2bf(v.y); o.z = f2bf(v.z); o.w = f2bf(v.w);
            reinterpret_cast<ushort4*>(xbf)[i] = o;
        }
        return;
    }
    b -= castBlocks;
    if (b < 256) {
        const float* Wl = (b < 128) ? Wl1 : Wl2;
        const float* Wr = (b < 128) ? Wr1 : Wr2;
        ushort* Wt = (b < 128) ? Wt1 : Wt2;
        int idx = (b & 127) * 256 + t;   // 128*256 = 32768
        int nn = idx >> 8, k = idx & 255;
        float v = (k < 128) ? Wl[k * 128 + nn] : Wr[(k - 128) * 128 + nn];
        Wt[nn * 256 + k] = f2bf(v);
        return;
    }
    // zero role: dbin[64] + relcur[64]
    if (t < 128) dzero[t] = 0;
}

__global__ __launch_bounds__(1024) void k_hscan(int* __restrict__ hist,
                                                int* __restrict__ bbase,
                                                int nblk, int NB, int E) {
    __shared__ int part[4][256];
    __shared__ int s[256];
    int t = threadIdx.x;
    int b = t & 255, g = t >> 8;
    int q = (nblk + 3) >> 2;
    int lo = g * q, hi = min(lo + q, nblk);
    int sum = 0;
    if (b < NB)
        for (int blk = lo; blk < hi; ++blk) sum += hist[blk * NB + b];
    part[g][b] = sum;
    __syncthreads();
    if (g == 0) s[b] = part[0][b] + part[1][b] + part[2][b] + part[3][b];
    __syncthreads();
    for (int off = 1; off < 256; off <<= 1) {
        int v = 0;
        if (g == 0 && b >= off) v = s[b - off];
        __syncthreads();
        if (g == 0) s[b] += v;
        __syncthreads();
    }
    int base = (b == 0) ? 0 : s[b - 1];
    if (g == 0 && b < NB) bbase[b] = base;
    if (t == 0) bbase[NB] = E;
    int run = base;
    for (int gg = 0; gg < g; ++gg) run += part[gg][b];
    if (b < NB)
        for (int blk = lo; blk < hi; ++blk) {
            int tmp = hist[blk * NB + b];
            hist[blk * NB + b] = run;
            run += tmp;
        }
}

__global__ __launch_bounds__(256) void k_scatter(const int* __restrict__ ei,
                                                 const int* __restrict__ hist,
                                                 uint* __restrict__ pairs, int E, int NB) {
    __shared__ int lofs[256];
    __shared__ int lh[256];
    int t = threadIdx.x;
    int blk = blockIdx.x;
    lh[t] = 0;
    if (t < NB) lofs[t] = hist[blk * NB + t];
    __syncthreads();
    int e0 = blk * CHUNK, e1 = min(e0 + CHUNK, E);
    for (int e = e0 + t; e < e1; e += 256) {
        int sN = ei[e];
        int d = ei[E + e];
        int b = d >> BSH;
        int lp = atomicAdd(&lh[b], 1);
        pairs[lofs[b] + lp] = ((uint)(d & 255) << 16) | (uint)sN;
    }
}

// count + scan + rowptr + fill + degree-histogram in ONE kernel
__global__ __launch_bounds__(256) void k_csr(const uint* __restrict__ pairs,
                                             const int* __restrict__ bbase,
                                             int* __restrict__ rowptr,
                                             ushort* __restrict__ eidx,
                                             int* __restrict__ dbin,
                                             int n, int E, int NB) {
    __shared__ int lc[256];
    __shared__ int cur[256];
    __shared__ int dh[64];
    int t = threadIdx.x;
    int b = blockIdx.x;
    int node0 = b << BSH;
    lc[t] = 0;
    if (t < 64) dh[t] = 0;
    __syncthreads();
    int r0 = bbase[b], r1 = bbase[b + 1];
    for (int i = r0 + t; i < r1; i += 256)
        atomicAdd(&lc[pairs[i] >> 16], 1);
    __syncthreads();
    int c0 = lc[t];
#pragma unroll
    for (int off = 1; off < 256; off <<= 1) {
        int u = (t >= off) ? lc[t - off] : 0;
        __syncthreads();
        lc[t] += u;
        __syncthreads();
    }
    int rp = r0 + lc[t] - c0;
    int node = node0 + t;
    if (node < n) {
        rowptr[node] = rp;
        atomicAdd(&dh[min(c0, 63)], 1);
    }
    if (b == NB - 1 && t == 0) rowptr[n] = E;
    cur[t] = rp;
    __syncthreads();
    if (t < 64) atomicAdd(&dbin[t], dh[t]);
    for (int i = r0 + t; i < r1; i += 256) {
        uint pr = pairs[i];
        int p = atomicAdd(&cur[pr >> 16], 1);
        eidx[p] = (ushort)(pr & 0xFFFFu);
    }
}

// degree-sorted permutation fill: each block re-derives the 64-bin exclusive
// prefix from the completed dbin locally, claims slots via relcur atomics.
__global__ __launch_bounds__(256) void k_dfill(const int* __restrict__ rowptr,
                                               const int* __restrict__ dbin,
                                               int* __restrict__ relcur,
                                               int* __restrict__ perm, int n) {
    __shared__ int lh[64], lbase[64], pre[64];
    int t = threadIdx.x;
    if (t < 64) lh[t] = 0;
    __syncthreads();
    int i = blockIdx.x * 256 + t;
    int d = -1;
    if (i < n) {
        d = rowptr[i + 1] - rowptr[i];
        if (d > 63) d = 63;
        atomicAdd(&lh[d], 1);
    }
    __syncthreads();
    if (t < 64) pre[t] = dbin[t];
    __syncthreads();
    for (int off = 1; off < 64; off <<= 1) {
        int v = (t < 64 && t >= off) ? pre[t - off] : 0;
        __syncthreads();
        if (t < 64) pre[t] += v;
        __syncthreads();
    }
    if (t < 64) {
        int base = (t == 0) ? 0 : pre[t - 1];
        lbase[t] = base + atomicAdd(&relcur[t], lh[t]);
        lh[t] = 0;
    }
    __syncthreads();
    if (i < n) {
        int lp = atomicAdd(&lh[d], 1);
        perm[lbase[d] + lp] = i;
    }
}

// ---------------- fused SAGE layer (degree-balanced via perm) ----------------
// Block = 32 slots (similar-degree nodes), 512 thr, __launch_bounds__(512,6):
// VGPR~40, no spill (NOTE: (512,8) forces VGPR 32 -> gather spills, dur 50->81).

#define ACC8(v)                                    \
    acc[0] += __uint_as_float((v).x << 16);        \
    acc[1] += __uint_as_float((v).x & 0xffff0000u);\
    acc[2] += __uint_as_float((v).y << 16);        \
    acc[3] += __uint_as_float((v).y & 0xffff0000u);\
    acc[4] += __uint_as_float((v).z << 16);        \
    acc[5] += __uint_as_float((v).z & 0xffff0000u);\
    acc[6] += __uint_as_float((v).w << 16);        \
    acc[7] += __uint_as_float((v).w & 0xffff0000u);

__global__ __launch_bounds__(512, 6) void k_fused(const ushort* __restrict__ hin,
                                                  const int* __restrict__ rowptr,
                                                  const ushort* __restrict__ eidx,
                                                  const int* __restrict__ perm,
                                                  const ushort* __restrict__ Wt,
                                                  const float* __restrict__ bias,
                                                  void* __restrict__ outp,
                                                  int n, int relu, int outBf16) {
    __shared__ ushort sagg[32][128];    // 8 KB
    __shared__ ushort sroot[32][128];   // 8 KB
    __shared__ int sperm[32];

    int t = threadIdx.x;
    int node0 = blockIdx.x * 32;

    if (t < 32) {
        int slot = node0 + t;
        sperm[t] = (slot < n) ? perm[slot] : (n - 1);
    }
    __syncthreads();

    // ---- Phase A: stage root half (32 rows x 16 chunks, 1 chunk/thread) ----
    {
        int r = t >> 4, c = t & 15;
        int row = sperm[r];
        uint4 v = *reinterpret_cast<const uint4*>(hin + (size_t)row * DD + c * 8);
        int cs = c ^ (r & 15);
        *reinterpret_cast<uint4*>(&sroot[r][cs * 8]) = v;
    }

    // ---- Phase B: gather-aggregate, 4 slots per wave ----
    int wave = t >> 6;
    int lane = t & 63;
    int grp = lane >> 4;
    int c16 = lane & 15;
    {
        int node = sperm[wave * 4 + grp];
        int beg = rowptr[node], end = rowptr[node + 1];
        const uint4* base = reinterpret_cast<const uint4*>(hin);

        float acc[8];
#pragma unroll
        for (int i = 0; i < 8; ++i) acc[i] = 0.f;

        int e = beg;
        for (; e + 8 <= end; e += 8) {
            int id[8];
            uint4 v[8];
#pragma unroll
            for (int j = 0; j < 8; ++j) id[j] = eidx[e + j];
#pragma unroll
            for (int j = 0; j < 8; ++j) v[j] = base[(size_t)id[j] * 16 + c16];
#pragma unroll
            for (int j = 0; j < 8; ++j) { ACC8(v[j]); }
        }
        for (; e < end; e += 4) {
            int m = end - e;
            int i0 = eidx[e];
            int i1 = eidx[e + (m > 1 ? 1 : 0)];
            int i2 = eidx[e + (m > 2 ? 2 : 0)];
            int i3 = eidx[e + (m > 3 ? 3 : 0)];
            uint4 v0 = base[(size_t)i0 * 16 + c16];
            uint4 v1 = base[(size_t)i1 * 16 + c16];
            uint4 v2 = base[(size_t)i2 * 16 + c16];
            uint4 v3 = base[(size_t)i3 * 16 + c16];
            ACC8(v0);
            if (m > 1) { ACC8(v1); }
            if (m > 2) { ACC8(v2); }
            if (m > 3) { ACC8(v3); }
        }

        float inv = 1.0f / fmaxf((float)(end - beg), 1.0f);
        uint4 o;
        o.x = ((uint)f2bf(acc[1] * inv) << 16) | (uint)f2bf(acc[0] * inv);
        o.y = ((uint)f2bf(acc[3] * inv) << 16) | (uint)f2bf(acc[2] * inv);
        o.z = ((uint)f2bf(acc[5] * inv) << 16) | (uint)f2bf(acc[4] * inv);
        o.w = ((uint)f2bf(acc[7] * inv) << 16) | (uint)f2bf(acc[6] * inv);
        int r = wave * 4 + grp;
        int cs = c16 ^ (r & 15);
        *reinterpret_cast<uint4*>(&sagg[r][cs * 8]) = o;
    }
    __syncthreads();

    // ---- Phase C: MFMA GEMM for this block's 32 rows ----
    int lr = lane & 15;
    int lk = lane >> 4;
    int nt = wave;            // 16-col slice

    short8v bf[8];
    const ushort* wbase = Wt + (size_t)(nt * 16 + lr) * 256 + lk * 8;
#pragma unroll
    for (int ks = 0; ks < 8; ++ks)
        bf[ks] = *reinterpret_cast<const short8v*>(wbase + ks * 32);

    int col = nt * 16 + lr;
    float bv = bias[col];

#pragma unroll
    for (int sub = 0; sub < 2; ++sub) {
        int m0 = sub * 16;
        int r = m0 + lr;
        f32x4 acc = (f32x4){0.f, 0.f, 0.f, 0.f};
#pragma unroll
        for (int ks = 0; ks < 4; ++ks) {          // agg half (K = 0..127)
            int cc = ks * 4 + lk;
            int cs = cc ^ (r & 15);
            short8v af = *reinterpret_cast<const short8v*>(&sagg[r][cs * 8]);
            acc = __builtin_amdgcn_mfma_f32_16x16x32_bf16(af, bf[ks], acc, 0, 0, 0);
        }
#pragma unroll
        for (int ks = 0; ks < 4; ++ks) {          // root half (K = 128..255)
            int cc = ks * 4 + lk;
            int cs = cc ^ (r & 15);
            short8v af = *reinterpret_cast<const short8v*>(&sroot[r][cs * 8]);
            acc = __builtin_amdgcn_mfma_f32_16x16x32_bf16(af, bf[ks + 4], acc, 0, 0, 0);
        }

        int slotb = m0 + lk * 4;
#pragma unroll
        for (int q = 0; q < 4; ++q) {
            int row = sperm[slotb + q];
            float v = acc[q] + bv;
            if (relu) v = fmaxf(v, 0.f);
            if (outBf16) {
                reinterpret_cast<ushort*>(outp)[(size_t)row * DD + col] = f2bf(v);
            } else {
                reinterpret_cast<float*>(outp)[(size_t)row * DD + col] = v;
            }
        }
    }
}

// ---------------- launch ----------------

extern "C" void kernel_launch(void* const* d_in, const int* in_sizes, int n_in,
                              void* d_out, int out_size, void* d_ws, size_t ws_size,
                              hipStream_t stream) {
    const float* x   = (const float*)d_in[0];
    const int*   ei  = (const int*)d_in[1];
    const float* Wl1 = (const float*)d_in[2];
    const float* Wr1 = (const float*)d_in[3];
    const float* b1  = (const float*)d_in[4];
    const float* Wl2 = (const float*)d_in[5];
    const float* Wr2 = (const float*)d_in[6];
    const float* b2  = (const float*)d_in[7];
    float* out = (float*)d_out;

    int n = in_sizes[0] / DD;
    int E = in_sizes[1] / 2;

    int NB   = (n + 255) >> 8;          // buckets (<=256 for n<=65536)
    int nblk = (E + CHUNK - 1) / CHUNK; // partition chunks

    char* ws = (char*)d_ws;
    size_t off = 0;
    auto take = [&](size_t bytes) -> void* {
        void* p = ws + off;
        off = (off + bytes + 255) & ~(size_t)255;
        return p;
    };
    int* rowptr    = (int*)take(((size_t)n + 1) * 4);
    int* hist      = (int*)take((size_t)nblk * NB * 4);
    int* bbase     = (int*)take(((size_t)NB + 1) * 4);
    int* dzero     = (int*)take(128 * 4);      // dbin[64] + relcur[64]
    int* dbin      = dzero;
    int* relcur    = dzero + 64;
    int* perm      = (int*)take((size_t)n * 4);
    ushort* eidx   = (ushort*)take((size_t)E * 2 + 16);
    uint* pairs    = (uint*)take((size_t)E * 4);
    ushort* xbf    = (ushort*)take((size_t)n * DD * 2);
    ushort* hbf    = (ushort*)take((size_t)n * DD * 2);
    ushort* Wt1    = (ushort*)take((size_t)DD * 256 * 2);
    ushort* Wt2    = (ushort*)take((size_t)DD * 256 * 2);

    int n4 = n * DD / 4;
    int castBlocks = (n4 + 255) / 256;
    int prepBlocks = nblk + castBlocks + 256 + 1;   // +1 zero role
    int nodeBlocks = (n + 255) / 256;

    k_prep<<<prepBlocks, 256, 0, stream>>>(ei, hist, E, NB, nblk,
                                           x, xbf, n4, castBlocks,
                                           Wl1, Wr1, Wt1, Wl2, Wr2, Wt2, dzero);
    k_hscan<<<1, 1024, 0, stream>>>(hist, bbase, nblk, NB, E);
    k_scatter<<<nblk, 256, 0, stream>>>(ei, hist, pairs, E, NB);
    k_csr<<<NB, 256, 0, stream>>>(pairs, bbase, rowptr, eidx, dbin, n, E, NB);
    k_dfill<<<nodeBlocks, 256, 0, stream>>>(rowptr, dbin, relcur, perm, n);

    int fusedBlocks = (n + 31) / 32;

    // Layer 1: hbf = relu(mean_agg(xbf) @ Wl1 + b1 + xbf @ Wr1)   [bf16 out]
    k_fused<<<fusedBlocks, 512, 0, stream>>>(xbf, rowptr, eidx, perm, Wt1, b1, hbf, n, 1, 1);
    // Layer 2: out = mean_agg(hbf) @ Wl2 + b2 + hbf @ Wr2          [fp32 out]
    k_fused<<<fusedBlocks, 512, 0, stream>>>(hbf, rowptr, eidx, perm, Wt2, b2, out, n, 0, 0);
}